// Round 1
// baseline (263.667 us; speedup 1.0000x reference)
//
#include <hip/hip_runtime.h>
#include <hip/hip_bf16.h>
#include <math.h>

#define BDIM 8
#define NPTS 2048
#define KNN 20
#define NCH 64
#define EPSV 1e-6f

// ---------------------------------------------------------------------------
// Kernel 1: exact 20-NN by iterative wave-argmax.
// One wave (64 lanes) per row n; each lane holds 32 candidate distances in
// registers (fully unrolled indexing -> no scratch).
// neg_dist[n][m] = 2*<p_n,p_m> - |p_n|^2 - |p_m|^2  (matches reference)
// ---------------------------------------------------------------------------
__global__ __launch_bounds__(256) void knn_kernel(const float* __restrict__ y,
                                                  int* __restrict__ idx_out) {
    const int wave = threadIdx.x >> 6;
    const int lane = threadIdx.x & 63;
    const int n = blockIdx.x * 4 + wave;
    const int b = blockIdx.y;
    const float* yb = y + (size_t)b * 3 * NPTS;

    const float yn0 = yb[n], yn1 = yb[NPTS + n], yn2 = yb[2 * NPTS + n];
    const float xxn = yn0 * yn0 + yn1 * yn1 + yn2 * yn2;

    float dist[32];
#pragma unroll
    for (int j = 0; j < 32; ++j) {
        const int m = lane + 64 * j;
        const float m0 = yb[m], m1 = yb[NPTS + m], m2 = yb[2 * NPTS + m];
        const float inner = yn0 * m0 + yn1 * m1 + yn2 * m2;
        const float xxm = m0 * m0 + m1 * m1 + m2 * m2;
        dist[j] = 2.0f * inner - xxn - xxm;
    }

    int my_sel = 0;
    for (int i = 0; i < KNN; ++i) {
        // per-lane argmax over 32 register values (static indexing)
        float bv = dist[0];
        int bj = 0;
#pragma unroll
        for (int j = 1; j < 32; ++j) {
            if (dist[j] > bv) { bv = dist[j]; bj = j; }
        }
        int bm = lane + 64 * bj;
        // wave-wide argmax (deterministic tie-break: smaller m)
        for (int off = 32; off > 0; off >>= 1) {
            const float ov = __shfl_xor(bv, off);
            const int om = __shfl_xor(bm, off);
            if (ov > bv || (ov == bv && om < bm)) { bv = ov; bm = om; }
        }
        // owner lane retires the winner
        if (lane == (bm & 63)) {
            const int jwin = bm >> 6;
#pragma unroll
            for (int jj = 0; jj < 32; ++jj)
                if (jj == jwin) dist[jj] = -INFINITY;
        }
        if (lane == i) my_sel = bm;
    }
    if (lane < KNN) idx_out[((size_t)(b * NPTS + n)) * KNN + lane] = my_sel;
}

// ---------------------------------------------------------------------------
// Kernel 2: fused VN-linear/leaky + channel-equivariant normalize + attention.
// One wave per point (b,n); lane = channel c (0..63).
// ---------------------------------------------------------------------------
__global__ __launch_bounds__(256) void vn_atten_kernel(
    const float* __restrict__ x, const float* __restrict__ y,
    const float* __restrict__ Wf1, const float* __restrict__ Wd1,
    const float* __restrict__ Wf2, const float* __restrict__ Wd2,
    const int* __restrict__ idx, float* __restrict__ out) {
    const int wave = threadIdx.x >> 6;
    const int c = threadIdx.x & 63;  // channel
    const int n = blockIdx.x * 4 + wave;
    const int b = blockIdx.y;

    // ---- q_x[b, c, :, n] -------------------------------------------------
    const float x0 = x[((size_t)b * 3 + 0) * NPTS + n];
    const float x1 = x[((size_t)b * 3 + 1) * NPTS + n];
    const float x2 = x[((size_t)b * 3 + 2) * NPTS + n];
    const float xx = x0 * x0 + x1 * x1 + x2 * x2;
    const float f = Wf1[c], g = Wd1[c];
    const float dot1 = f * g * xx;
    const float d21 = g * g * xx;
    const float coef1 = dot1 / (d21 + EPSV);
    const float s_neg = f - coef1 * g;                 // coefficient of x in 'neg'
    const float s = 0.2f * f + 0.8f * ((dot1 >= 0.0f) ? f : s_neg);
    const float q0 = s * x0, q1 = s * x1, q2 = s * x2;
    const float qn2 = q0 * q0 + q1 * q1 + q2 * q2;
    const float qn = sqrtf(qn2);
    float totq = qn2;
#pragma unroll
    for (int off = 1; off < 64; off <<= 1) totq += __shfl_xor(totq, off);
    const float qscale = (1.0f / fmaxf(qn, 1e-12f)) * (qn / fmaxf(sqrtf(totq), 1e-12f));
    const float qx0 = q0 * qscale, qx1 = q1 * qscale, qx2 = q2 * qscale;

    // ---- per-neighbor VN features + attention logits ---------------------
    const float* yb = y + (size_t)b * 3 * NPTS;
    const float yn0 = yb[n], yn1 = yb[NPTS + n], yn2 = yb[2 * NPTS + n];
    const float wf0 = Wf2[2 * c], wf1 = Wf2[2 * c + 1];
    const float wd0 = Wd2[2 * c], wd1 = Wd2[2 * c + 1];
    const int* idxp = idx + ((size_t)(b * NPTS + n)) * KNN;

    float yf0[KNN], yf1[KNN], yf2[KNN];
    float sk[KNN];

#pragma unroll
    for (int k = 0; k < KNN; ++k) {
        const int m = idxp[k];
        const float e0 = yb[m] - yn0;
        const float e1 = yb[NPTS + m] - yn1;
        const float e2 = yb[2 * NPTS + m] - yn2;
        // p = wf0*edge + wf1*center ; d = wd0*edge + wd1*center
        const float p0 = wf0 * e0 + wf1 * yn0;
        const float p1 = wf0 * e1 + wf1 * yn1;
        const float p2 = wf0 * e2 + wf1 * yn2;
        const float dv0 = wd0 * e0 + wd1 * yn0;
        const float dv1 = wd0 * e1 + wd1 * yn1;
        const float dv2 = wd0 * e2 + wd1 * yn2;
        const float dt = p0 * dv0 + p1 * dv1 + p2 * dv2;
        const float dd = dv0 * dv0 + dv1 * dv1 + dv2 * dv2;
        const float cf = dt / (dd + EPSV);
        float v0, v1, v2;
        if (dt >= 0.0f) {
            v0 = p0; v1 = p1; v2 = p2;
        } else {
            v0 = p0 - cf * dv0; v1 = p1 - cf * dv1; v2 = p2 - cf * dv2;
        }
        v0 = 0.2f * p0 + 0.8f * v0;
        v1 = 0.2f * p1 + 0.8f * v1;
        v2 = 0.2f * p2 + 0.8f * v2;
        yf0[k] = v0; yf1[k] = v1; yf2[k] = v2;

        const float nn2 = v0 * v0 + v1 * v1 + v2 * v2;
        const float nrm = sqrtf(nn2);
        float tot = nn2;
#pragma unroll
        for (int off = 1; off < 64; off <<= 1) tot += __shfl_xor(tot, off);
        const float qk = (v0 * qx0 + v1 * qx1 + v2 * qx2) *
                         (1.0f / fmaxf(nrm, 1e-12f)) *
                         (nrm / fmaxf(sqrtf(tot), 1e-12f));
        // head (16-channel) reduce: lanes with same c>>4
        float hs = qk;
#pragma unroll
        for (int off = 1; off < 16; off <<= 1) hs += __shfl_xor(hs, off);
        sk[k] = hs * 0.14433756729740643f;  // 1/sqrt(3*16)
    }

    // ---- softmax over k (per-lane, register resident) --------------------
    float mx = sk[0];
#pragma unroll
    for (int k = 1; k < KNN; ++k) mx = fmaxf(mx, sk[k]);
    float se = 0.0f;
#pragma unroll
    for (int k = 0; k < KNN; ++k) {
        sk[k] = __expf(sk[k] - mx);
        se += sk[k];
    }
    const float inv = 1.0f / se;

    float o0 = 0.0f, o1 = 0.0f, o2 = 0.0f;
#pragma unroll
    for (int k = 0; k < KNN; ++k) {
        const float a = sk[k] * inv;
        o0 += a * yf0[k];
        o1 += a * yf1[k];
        o2 += a * yf2[k];
    }

    float* ob = out + (((size_t)b * NCH + c) * 3) * NPTS + n;
    ob[0] = o0;
    ob[NPTS] = o1;
    ob[2 * NPTS] = o2;
}

extern "C" void kernel_launch(void* const* d_in, const int* in_sizes, int n_in,
                              void* d_out, int out_size, void* d_ws, size_t ws_size,
                              hipStream_t stream) {
    const float* x = (const float*)d_in[0];
    const float* y = (const float*)d_in[1];
    const float* Wf1 = (const float*)d_in[2];
    const float* Wd1 = (const float*)d_in[3];
    const float* Wf2 = (const float*)d_in[4];
    const float* Wd2 = (const float*)d_in[5];
    float* out = (float*)d_out;
    int* idx = (int*)d_ws;  // B*N*KNN ints = 1.31 MB

    dim3 grid(NPTS / 4, BDIM);
    knn_kernel<<<grid, 256, 0, stream>>>(y, idx);
    vn_atten_kernel<<<grid, 256, 0, stream>>>(x, y, Wf1, Wd1, Wf2, Wd2, idx, out);
}

// Round 2
// 189.831 us; speedup vs baseline: 1.3890x; 1.3890x over previous
//
#include <hip/hip_runtime.h>
#include <hip/hip_bf16.h>
#include <math.h>

#define BDIM 8
#define NPTS 2048
#define KNN 20
#define NCH 64
#define EPSV 1e-6f
#define CMAX 512

// 1-instruction cross-lane xor swizzle (BitMode: offset = (xor<<10)|0x1F), xor<=16
#define SWZ(v, code) __uint_as_float(__builtin_amdgcn_ds_swizzle(__float_as_uint(v), (code)))

// ---------------------------------------------------------------------------
// Kernel 1: exact 20-NN via threshold + rank-count selection.
// One wave per row n. Lane owns 32 contiguous candidates m = lane*32 + j.
//  tau = 20th-largest of the 64 per-lane maxima  (valid lower bound on the
//  true 20th-largest: the 20 popped lane maxima are >= tau). Candidates
//  >= tau (C >= 20, expected ~25) are compacted to LDS; exact top-20 by
//  pairwise rank counting with (value, smaller-index) tie-break = jax.top_k.
// ---------------------------------------------------------------------------
__global__ __launch_bounds__(256) void knn_kernel(const float* __restrict__ y,
                                                  int* __restrict__ idx_out) {
    __shared__ uint2 cand[4][CMAX];
    const int wave = threadIdx.x >> 6;
    const int lane = threadIdx.x & 63;
    const int n = blockIdx.x * 4 + wave;
    const int b = blockIdx.y;
    const float* yb = y + (size_t)b * 3 * NPTS;

    const float yn0 = yb[n], yn1 = yb[NPTS + n], yn2 = yb[2 * NPTS + n];
    const float xxn = yn0 * yn0 + yn1 * yn1 + yn2 * yn2;

    // coalesced float4 loads: lane's chunk is 32 contiguous floats per row
    const int base_m = lane * 32;
    const float4* r0 = (const float4*)(yb + base_m);
    const float4* r1 = (const float4*)(yb + NPTS + base_m);
    const float4* r2 = (const float4*)(yb + 2 * NPTS + base_m);

    float dist[32];
#pragma unroll
    for (int q = 0; q < 8; ++q) {
        const float4 a0 = r0[q], a1 = r1[q], a2 = r2[q];
#define DCOMP(t, c0, c1, c2)                                              \
        dist[q * 4 + t] = 2.0f * (yn0 * (c0) + yn1 * (c1) + yn2 * (c2)) - \
                          xxn - ((c0) * (c0) + (c1) * (c1) + (c2) * (c2));
        DCOMP(0, a0.x, a1.x, a2.x)
        DCOMP(1, a0.y, a1.y, a2.y)
        DCOMP(2, a0.z, a1.z, a2.z)
        DCOMP(3, a0.w, a1.w, a2.w)
#undef DCOMP
    }

    // per-lane max (values only)
    float lmax = dist[0];
#pragma unroll
    for (int j = 1; j < 32; ++j) lmax = fmaxf(lmax, dist[j]);

    // tau = 20th-largest of the 64 lane maxima (value-only butterfly pops)
    float bv = lmax, tau = 0.0f;
    for (int i = 0; i < KNN; ++i) {
        float wv = bv;
        wv = fmaxf(wv, SWZ(wv, 0x041F));
        wv = fmaxf(wv, SWZ(wv, 0x081F));
        wv = fmaxf(wv, SWZ(wv, 0x101F));
        wv = fmaxf(wv, SWZ(wv, 0x201F));
        wv = fmaxf(wv, SWZ(wv, 0x401F));
        wv = fmaxf(wv, __shfl_xor(wv, 32));
        tau = wv;
        const unsigned long long own = __ballot(bv == wv);
        if (lane == (int)(__ffsll((long long)own) - 1)) bv = -INFINITY;
    }

    // mark candidates >= tau
    unsigned cmask = 0;
    int lc = 0;
#pragma unroll
    for (int j = 0; j < 32; ++j) {
        if (dist[j] >= tau) { cmask |= (1u << j); ++lc; }
    }
    // exclusive prefix over lanes for compaction slots
    int incl = lc;
#pragma unroll
    for (int off = 1; off < 64; off <<= 1) {
        const int t = __shfl_up(incl, off);
        if (lane >= off) incl += t;
    }
    const int cbase = incl - lc;
    const int C = __shfl(incl, 63);

    // stage (value_bits, m) pairs to LDS
    int slot = cbase;
#pragma unroll
    for (int j = 0; j < 32; ++j) {
        if (cmask & (1u << j)) {
            if (slot < CMAX) cand[wave][slot] = make_uint2(__float_as_uint(dist[j]),
                                                          (unsigned)(base_m + j));
            ++slot;
        }
    }
    __syncthreads();

    int* orow = idx_out + ((size_t)(b * NPTS + n)) * KNN;
    const int Cc = (C < CMAX) ? C : CMAX;
    if (Cc <= 64) {
        // common path: one candidate per lane
        const int t = (lane < Cc) ? lane : 0;
        const uint2 e = cand[wave][t];
        const float v = __uint_as_float(e.x);
        const int mm = (int)e.y;
        int rank = 0;
        for (int s = 0; s < Cc; ++s) {
            const uint2 o = cand[wave][s];
            const float ov = __uint_as_float(o.x);
            rank += (ov > v || (ov == v && (int)o.y < mm)) ? 1 : 0;
        }
        if (lane < Cc && rank < KNN) orow[rank] = mm;
    } else {
        // rare fallback (C up to CMAX)
        for (int r = 0; r < CMAX / 64; ++r) {
            const int t = lane + 64 * r;
            if (t < Cc) {
                const uint2 e = cand[wave][t];
                const float v = __uint_as_float(e.x);
                const int mm = (int)e.y;
                int rank = 0;
                for (int s = 0; s < Cc; ++s) {
                    const uint2 o = cand[wave][s];
                    const float ov = __uint_as_float(o.x);
                    rank += (ov > v || (ov == v && (int)o.y < mm)) ? 1 : 0;
                }
                if (rank < KNN) orow[rank] = mm;
            }
        }
    }
}

// ---------------------------------------------------------------------------
// Kernel 2: fused VN-linear/leaky + channel-equi normalize + attention.
// One wave per point (b,n); lane = channel. Online softmax over k (no
// yf/sk register arrays -> ~half the VGPRs), ds_swizzle reductions,
// int4-batched idx loads, 1-deep pipeline on the y gathers.
// ---------------------------------------------------------------------------
__global__ __launch_bounds__(256) void vn_atten_kernel(
    const float* __restrict__ x, const float* __restrict__ y,
    const float* __restrict__ Wf1, const float* __restrict__ Wd1,
    const float* __restrict__ Wf2, const float* __restrict__ Wd2,
    const int* __restrict__ idx, float* __restrict__ out) {
    const int wave = threadIdx.x >> 6;
    const int c = threadIdx.x & 63;  // channel
    const int n = blockIdx.x * 4 + wave;
    const int b = blockIdx.y;

    // ---- q_x ------------------------------------------------------------
    const float x0 = x[((size_t)b * 3 + 0) * NPTS + n];
    const float x1 = x[((size_t)b * 3 + 1) * NPTS + n];
    const float x2 = x[((size_t)b * 3 + 2) * NPTS + n];
    const float xx = x0 * x0 + x1 * x1 + x2 * x2;
    const float f = Wf1[c], g = Wd1[c];
    const float dot1 = f * g * xx;
    const float d21 = g * g * xx;
    const float coef1 = dot1 / (d21 + EPSV);
    const float s_neg = f - coef1 * g;
    const float sxc = 0.2f * f + 0.8f * ((dot1 >= 0.0f) ? f : s_neg);
    const float q0 = sxc * x0, q1 = sxc * x1, q2 = sxc * x2;
    const float qn2 = q0 * q0 + q1 * q1 + q2 * q2;
    const float qn = sqrtf(qn2);
    float totq = qn2;
    totq += SWZ(totq, 0x041F);
    totq += SWZ(totq, 0x081F);
    totq += SWZ(totq, 0x101F);
    totq += SWZ(totq, 0x201F);
    totq += SWZ(totq, 0x401F);
    totq += __shfl_xor(totq, 32);
    const float qscale = (1.0f / fmaxf(qn, 1e-12f)) * (qn / fmaxf(sqrtf(totq), 1e-12f));
    const float qx0 = q0 * qscale, qx1 = q1 * qscale, qx2 = q2 * qscale;

    // ---- neighbors -------------------------------------------------------
    const float* yb = y + (size_t)b * 3 * NPTS;
    const float yn0 = yb[n], yn1 = yb[NPTS + n], yn2 = yb[2 * NPTS + n];
    const float wf0 = Wf2[2 * c], wf1 = Wf2[2 * c + 1];
    const float wd0 = Wd2[2 * c], wd1 = Wd2[2 * c + 1];

    const int4* ip = (const int4*)(idx + ((size_t)(b * NPTS + n)) * KNN);  // 80B rows: 16B-aligned
    const int4 i0 = ip[0], i1 = ip[1], i2 = ip[2], i3 = ip[3], i4 = ip[4];
    const int ms[KNN] = {i0.x, i0.y, i0.z, i0.w, i1.x, i1.y, i1.z, i1.w,
                         i2.x, i2.y, i2.z, i2.w, i3.x, i3.y, i3.z, i3.w,
                         i4.x, i4.y, i4.z, i4.w};

    float o0 = 0.0f, o1 = 0.0f, o2 = 0.0f;
    float mrun = -INFINITY, lsum = 0.0f;

    float p0 = yb[ms[0]], p1 = yb[NPTS + ms[0]], p2 = yb[2 * NPTS + ms[0]];
#pragma unroll
    for (int k = 0; k < KNN; ++k) {
        const float g0 = p0, g1 = p1, g2 = p2;
        if (k < KNN - 1) {
            const int mn = ms[k + 1];
            p0 = yb[mn]; p1 = yb[NPTS + mn]; p2 = yb[2 * NPTS + mn];
        }
        const float e0 = g0 - yn0, e1 = g1 - yn1, e2 = g2 - yn2;
        const float pp0 = wf0 * e0 + wf1 * yn0;
        const float pp1 = wf0 * e1 + wf1 * yn1;
        const float pp2 = wf0 * e2 + wf1 * yn2;
        const float dv0 = wd0 * e0 + wd1 * yn0;
        const float dv1 = wd0 * e1 + wd1 * yn1;
        const float dv2 = wd0 * e2 + wd1 * yn2;
        const float dt = pp0 * dv0 + pp1 * dv1 + pp2 * dv2;
        const float dd = dv0 * dv0 + dv1 * dv1 + dv2 * dv2;
        const float cf = dt / (dd + EPSV);
        float v0, v1, v2;
        if (dt >= 0.0f) {
            v0 = pp0; v1 = pp1; v2 = pp2;
        } else {
            v0 = pp0 - cf * dv0; v1 = pp1 - cf * dv1; v2 = pp2 - cf * dv2;
        }
        v0 = 0.2f * pp0 + 0.8f * v0;
        v1 = 0.2f * pp1 + 0.8f * v1;
        v2 = 0.2f * pp2 + 0.8f * v2;

        const float nn2 = v0 * v0 + v1 * v1 + v2 * v2;
        const float nrm = sqrtf(nn2);
        float tot = nn2;
        tot += SWZ(tot, 0x041F);
        tot += SWZ(tot, 0x081F);
        tot += SWZ(tot, 0x101F);
        tot += SWZ(tot, 0x201F);
        tot += SWZ(tot, 0x401F);
        tot += __shfl_xor(tot, 32);
        const float qk = (v0 * qx0 + v1 * qx1 + v2 * qx2) *
                         (1.0f / fmaxf(nrm, 1e-12f)) *
                         (nrm / fmaxf(sqrtf(tot), 1e-12f));
        float hs = qk;
        hs += SWZ(hs, 0x041F);
        hs += SWZ(hs, 0x081F);
        hs += SWZ(hs, 0x101F);
        hs += SWZ(hs, 0x201F);
        const float s = hs * 0.14433756729740643f;  // 1/sqrt(3*16)

        // online softmax update
        const float newm = fmaxf(mrun, s);
        const float sc = __expf(mrun - newm);
        const float pw = __expf(s - newm);
        lsum = lsum * sc + pw;
        o0 = o0 * sc + pw * v0;
        o1 = o1 * sc + pw * v1;
        o2 = o2 * sc + pw * v2;
        mrun = newm;
    }

    const float inv = 1.0f / lsum;
    float* ob = out + (((size_t)b * NCH + c) * 3) * NPTS + n;
    ob[0] = o0 * inv;
    ob[NPTS] = o1 * inv;
    ob[2 * NPTS] = o2 * inv;
}

extern "C" void kernel_launch(void* const* d_in, const int* in_sizes, int n_in,
                              void* d_out, int out_size, void* d_ws, size_t ws_size,
                              hipStream_t stream) {
    const float* x = (const float*)d_in[0];
    const float* y = (const float*)d_in[1];
    const float* Wf1 = (const float*)d_in[2];
    const float* Wd1 = (const float*)d_in[3];
    const float* Wf2 = (const float*)d_in[4];
    const float* Wd2 = (const float*)d_in[5];
    float* out = (float*)d_out;
    int* idx = (int*)d_ws;  // B*N*KNN ints

    dim3 grid(NPTS / 4, BDIM);
    knn_kernel<<<grid, 256, 0, stream>>>(y, idx);
    vn_atten_kernel<<<grid, 256, 0, stream>>>(x, y, Wf1, Wd1, Wf2, Wd2, idx, out);
}

// Round 4
// 149.802 us; speedup vs baseline: 1.7601x; 1.2672x over previous
//
#include <hip/hip_runtime.h>
#include <hip/hip_bf16.h>
#include <math.h>

#define BDIM 8
#define NPTS 2048
#define KNN 20
#define NCH 64
#define EPSV 1e-6f

// 1-instruction cross-lane xor swizzle (BitMode: offset=(xor<<10)|0x1F), xor<=16
#define SWZ(v, code) __uint_as_float(__builtin_amdgcn_ds_swizzle(__float_as_uint(v), (code)))

// ---------------------------------------------------------------------------
// Fused kernel: exact 20-NN + VN-linear/leaky + channel-equi normalize +
// head attention. One wave per point (b,n); lane = channel (vn phase).
// ---------------------------------------------------------------------------
__global__ __launch_bounds__(256) void fused_kernel(
    const float* __restrict__ x, const float* __restrict__ y,
    const float* __restrict__ Wf1, const float* __restrict__ Wd1,
    const float* __restrict__ Wf2, const float* __restrict__ Wd2,
    float* __restrict__ out) {
    __shared__ uint2 cand[4][64];          // knn candidate compaction
    __shared__ float4 gram[4][KNN][2];     // {ee,ey,ex,_},{e0,e1,e2,_}

    const int wave = threadIdx.x >> 6;
    const int lane = threadIdx.x & 63;
    const int n = blockIdx.x * 4 + wave;
    const int b = blockIdx.y;
    const float* yb = y + (size_t)b * 3 * NPTS;

    const float yn0 = yb[n], yn1 = yb[NPTS + n], yn2 = yb[2 * NPTS + n];
    const float xxn = yn0 * yn0 + yn1 * yn1 + yn2 * yn2;

    // ======================= KNN phase =====================================
    const int base_m = lane * 32;
    const float4* r0 = (const float4*)(yb + base_m);
    const float4* r1 = (const float4*)(yb + NPTS + base_m);
    const float4* r2 = (const float4*)(yb + 2 * NPTS + base_m);

    float dist[32];
#pragma unroll
    for (int q = 0; q < 8; ++q) {
        const float4 a0 = r0[q], a1 = r1[q], a2 = r2[q];
#define DCOMP(t, c0, c1, c2)                                              \
        dist[q * 4 + t] = 2.0f * (yn0 * (c0) + yn1 * (c1) + yn2 * (c2)) - \
                          xxn - ((c0) * (c0) + (c1) * (c1) + (c2) * (c2));
        DCOMP(0, a0.x, a1.x, a2.x)
        DCOMP(1, a0.y, a1.y, a2.y)
        DCOMP(2, a0.z, a1.z, a2.z)
        DCOMP(3, a0.w, a1.w, a2.w)
#undef DCOMP
    }

    // per-lane top-2 (values only)
    float t0 = dist[0], t1 = -INFINITY;
#pragma unroll
    for (int j = 1; j < 32; ++j) {
        const float v = dist[j];
        const float hi = fmaxf(t0, v), lo = fminf(t0, v);
        t0 = hi;
        t1 = fmaxf(t1, lo);
    }

    // bitonic sort (descending) of the 64 second-maxima; tau = 10th largest.
    // >=10 lanes have top2 >= tau, each contributing >=2 values >= tau.
    float key = t1;
#pragma unroll
    for (int size = 2; size <= 64; size <<= 1) {
#pragma unroll
        for (int stride = size >> 1; stride > 0; stride >>= 1) {
            const float other = __shfl_xor(key, stride);
            const bool low = (lane & stride) == 0;
            const bool up = (lane & size) == 0;
            key = (low == up) ? fmaxf(key, other) : fminf(key, other);
        }
    }
    const float tau = __shfl(key, 9);

    // mark + count candidates >= tau
    unsigned cmask = 0u;
    int lc = 0;
#pragma unroll
    for (int j = 0; j < 32; ++j)
        if (dist[j] >= tau) { cmask |= (1u << j); ++lc; }

    int incl = lc;
#pragma unroll
    for (int off = 1; off < 64; off <<= 1) {
        const int t = __shfl_up(incl, off);
        if (lane >= off) incl += t;
    }
    const int cbase = incl - lc;
    const int C = __shfl(incl, 63);

    if (C <= 64) {  // compact to LDS (wave-uniform branch)
        int slot = cbase;
#pragma unroll
        for (int j = 0; j < 32; ++j) {
            if (cmask & (1u << j)) {
                cand[wave][slot] = make_uint2(__float_as_uint(dist[j]),
                                              (unsigned)(base_m + j));
                ++slot;
            }
        }
    }
    __syncthreads();  // block-uniform point

    int mk = 0;  // lane<20: selected neighbor index
    if (C <= 64) {
        const int t = (lane < C) ? lane : 0;
        const uint2 e = cand[wave][t];
        unsigned uv = e.x;
        uv = (uv & 0x80000000u) ? ~uv : (uv | 0x80000000u);  // order-preserving
        unsigned long long kk = ((unsigned long long)(~uv) << 32) | (unsigned long long)e.y;
        if (lane >= C) kk = ~0ULL;
        // bitonic ascending sort: lane t = t-th largest dist
#pragma unroll
        for (int size = 2; size <= 64; size <<= 1) {
#pragma unroll
            for (int stride = size >> 1; stride > 0; stride >>= 1) {
                const unsigned long long o = __shfl_xor(kk, stride);
                const bool low = (lane & stride) == 0;
                const bool up = (lane & size) == 0;
                kk = (low == up) ? (kk < o ? kk : o) : (kk > o ? kk : o);
            }
        }
        mk = (int)(kk & 0xffffffffu);
    } else {
        // exact fallback (never taken with random data): 20 iterative pops
        int my_sel = 0;
        for (int i = 0; i < KNN; ++i) {
            float bv = dist[0];
            int bj = 0;
#pragma unroll
            for (int j = 1; j < 32; ++j)
                if (dist[j] > bv) { bv = dist[j]; bj = j; }
            int bm = base_m + bj;
            for (int off = 32; off > 0; off >>= 1) {
                const float ov = __shfl_xor(bv, off);
                const int om = __shfl_xor(bm, off);
                if (ov > bv || (ov == bv && om < bm)) { bv = ov; bm = om; }
            }
            if ((bm >> 5) == lane) {
                const int jw = bm & 31;
#pragma unroll
                for (int jj = 0; jj < 32; ++jj)
                    if (jj == jw) dist[jj] = -INFINITY;
            }
            if (lane == i) my_sel = bm;
        }
        mk = my_sel;
    }

    // ======================= VN-attention phase ============================
    const int c = lane;  // channel
    const float x0 = x[((size_t)b * 3 + 0) * NPTS + n];
    const float x1 = x[((size_t)b * 3 + 1) * NPTS + n];
    const float x2 = x[((size_t)b * 3 + 2) * NPTS + n];
    const float xx = x0 * x0 + x1 * x1 + x2 * x2;
    const float yy = xxn;
    const float yx = yn0 * x0 + yn1 * x1 + yn2 * x2;

    // q scalar: q_x = qs * x_vec
    const float f = Wf1[c], g = Wd1[c];
    const float dot1 = f * g * xx;
    const float d21 = g * g * xx;
    const float coef1 = dot1 / (d21 + EPSV);
    const float s_neg = f - coef1 * g;
    const float sxc = 0.2f * f + 0.8f * ((dot1 >= 0.0f) ? f : s_neg);
    const float qn2 = sxc * sxc * xx;
    float totq = qn2;
    totq += SWZ(totq, 0x041F);
    totq += SWZ(totq, 0x081F);
    totq += SWZ(totq, 0x101F);
    totq += SWZ(totq, 0x201F);
    totq += SWZ(totq, 0x401F);
    totq += __shfl_xor(totq, 32);
    const float qn = sqrtf(qn2);
    const float qscale = (1.0f / fmaxf(qn, 1e-12f)) * (qn / fmaxf(sqrtf(totq), 1e-12f));
    const float qs = sxc * qscale;

    // stage Gram values for this wave's 20 neighbors
    if (lane < KNN) {
        const float e0 = yb[mk] - yn0;
        const float e1 = yb[NPTS + mk] - yn1;
        const float e2 = yb[2 * NPTS + mk] - yn2;
        gram[wave][lane][0] = make_float4(e0 * e0 + e1 * e1 + e2 * e2,
                                          e0 * yn0 + e1 * yn1 + e2 * yn2,
                                          e0 * x0 + e1 * x1 + e2 * x2, 0.0f);
        gram[wave][lane][1] = make_float4(e0, e1, e2, 0.0f);
    }
    __syncthreads();

    // per-channel quadratic coefficients
    const float wf0 = Wf2[2 * c], wf1v = Wf2[2 * c + 1];
    const float wd0 = Wd2[2 * c], wd1v = Wd2[2 * c + 1];
    const float cA = wf0 * wd0, cB = wf0 * wd1v + wf1v * wd0, cC = wf1v * wd1v;
    const float dA = wd0 * wd0, dB = 2.0f * wd0 * wd1v, dC = wd1v * wd1v;

    float u[KNN], t2[KNN], hh[KNN];
#pragma unroll
    for (int k = 0; k < KNN; ++k) {
        const float4 gv = gram[wave][k][0];
        const float ee = gv.x, ey = gv.y, ex = gv.z;
        const float dt = cA * ee + cB * ey + cC * yy;
        const float dd = dA * ee + dB * ey + dC * yy;
        const float cf = dt * __builtin_amdgcn_rcpf(dd + EPSV);
        const float uu = (dt < 0.0f) ? 0.8f * cf : 0.0f;
        u[k] = uu;
        const float a = wf0 - uu * wd0;
        const float bb = wf1v - uu * wd1v;
        t2[k] = a * (a * ee + bb * ey) + bb * (a * ey + bb * yy);  // |v|^2
        hh[k] = qs * (a * ex + bb * yx);                           // <v, qx>
    }

    // batched butterfly reductions (independent chains -> pipelined)
#pragma unroll
    for (int k = 0; k < KNN; ++k) t2[k] += SWZ(t2[k], 0x041F);
#pragma unroll
    for (int k = 0; k < KNN; ++k) t2[k] += SWZ(t2[k], 0x081F);
#pragma unroll
    for (int k = 0; k < KNN; ++k) t2[k] += SWZ(t2[k], 0x101F);
#pragma unroll
    for (int k = 0; k < KNN; ++k) t2[k] += SWZ(t2[k], 0x201F);
#pragma unroll
    for (int k = 0; k < KNN; ++k) t2[k] += SWZ(t2[k], 0x401F);
#pragma unroll
    for (int k = 0; k < KNN; ++k) t2[k] += __shfl_xor(t2[k], 32);
    // head (16-lane) sums of <v,qx>
#pragma unroll
    for (int k = 0; k < KNN; ++k) hh[k] += SWZ(hh[k], 0x041F);
#pragma unroll
    for (int k = 0; k < KNN; ++k) hh[k] += SWZ(hh[k], 0x081F);
#pragma unroll
    for (int k = 0; k < KNN; ++k) hh[k] += SWZ(hh[k], 0x101F);
#pragma unroll
    for (int k = 0; k < KNN; ++k) hh[k] += SWZ(hh[k], 0x201F);

    // logits + softmax over k (register resident)
    float att[KNN];
    float mx = -INFINITY;
#pragma unroll
    for (int k = 0; k < KNN; ++k) {
        const float rs = __builtin_amdgcn_rsqf(fmaxf(t2[k], 1e-24f));
        att[k] = hh[k] * rs * 0.14433756729740643f;  // 1/sqrt(3*16)
        mx = fmaxf(mx, att[k]);
    }
    float se = 0.0f;
#pragma unroll
    for (int k = 0; k < KNN; ++k) {
        att[k] = __expf(att[k] - mx);
        se += att[k];
    }
    const float inv = __builtin_amdgcn_rcpf(se);

    // output: sum_k att*(a*e + b*yn)
    float o0 = 0.0f, o1 = 0.0f, o2 = 0.0f, bs = 0.0f;
#pragma unroll
    for (int k = 0; k < KNN; ++k) {
        const float4 ev = gram[wave][k][1];
        const float a = wf0 - u[k] * wd0;
        const float bb = wf1v - u[k] * wd1v;
        const float w = att[k] * inv;
        const float wa = w * a;
        bs += w * bb;
        o0 += wa * ev.x;
        o1 += wa * ev.y;
        o2 += wa * ev.z;
    }

    float* ob = out + (((size_t)b * NCH + c) * 3) * NPTS + n;
    ob[0] = o0 + bs * yn0;
    ob[NPTS] = o1 + bs * yn1;
    ob[2 * NPTS] = o2 + bs * yn2;
}

extern "C" void kernel_launch(void* const* d_in, const int* in_sizes, int n_in,
                              void* d_out, int out_size, void* d_ws, size_t ws_size,
                              hipStream_t stream) {
    const float* x = (const float*)d_in[0];
    const float* y = (const float*)d_in[1];
    const float* Wf1 = (const float*)d_in[2];
    const float* Wd1 = (const float*)d_in[3];
    const float* Wf2 = (const float*)d_in[4];
    const float* Wd2 = (const float*)d_in[5];
    float* out = (float*)d_out;

    dim3 grid(NPTS / 4, BDIM);
    fused_kernel<<<grid, 256, 0, stream>>>(x, y, Wf1, Wd1, Wf2, Wd2, out);
}